// Round 6
// baseline (929.332 us; speedup 1.0000x reference)
//
#include <hip/hip_runtime.h>

// ---------------------------------------------------------------------------
// GCN 2-layer: out = A_n @ relu(A_n @ (x W1) + b1) W2 + b2,  A_n = D^-1/2 A D^-1/2
// N=50000 nodes, E=800000 edges (+ implicit self loops), F: 128 -> 128 -> 64.
// CSR by dst (count -> scan -> fill), dense fp32 GEMMs, wave-per-node gather:
//   out_v = d_v*(sum_e d_s h_s + d_v h_v) + b
// R4 lesson: unbounded unroll+staging -> 256 VGPR spill catastrophe.
// R5 lesson: VGPR still 256 (no launch-bounds cap) -> 2 waves/SIMD, 8% occ,
//   VALUBusy 13%; 391 blocks is too few. Fix: 8x4/4x4 micro-tiles (BN=64),
//   782 blocks, __launch_bounds__(256,4) to force VGPR<=128, TN=4 makes Bs
//   reads 16B-stride (2-way bank aliasing = free).
// ---------------------------------------------------------------------------

#define N_NODES 50000
#define N_EDGES 800000

// workspace layout (bytes, all 256-aligned)
static constexpr size_t OFF_DEG  = 0;         // int[50000]
static constexpr size_t OFF_CUR  = 200192;    // int[50000]
static constexpr size_t OFF_ROW  = 400384;    // int[50001]
static constexpr size_t OFF_BS   = 600576;    // int[256]
static constexpr size_t OFF_DINV = 601600;    // float[50000]
static constexpr size_t OFF_CSR  = 801792;    // int[800000]
static constexpr size_t OFF_H1   = 4001792;   // float[50000*128]  (reused as h2)
static constexpr size_t OFF_OUT1 = 29601792;  // float[50000*128]
// total ~55.2 MB

__global__ __launch_bounds__(256) void count_deg_k(const int* __restrict__ ei,
                                                   int* __restrict__ deg) {
    int e = blockIdx.x * 256 + threadIdx.x;
    if (e < N_EDGES) {
        int d = ei[N_EDGES + e];
        if ((unsigned)d < N_NODES) atomicAdd(&deg[d], 1);
    }
}

__global__ __launch_bounds__(256) void dinv_k(const int* __restrict__ deg,
                                              float* __restrict__ dinv) {
    int i = blockIdx.x * 256 + threadIdx.x;
    if (i < N_NODES) dinv[i] = rsqrtf((float)(deg[i] + 1));  // +1 self loop
}

__global__ __launch_bounds__(256) void scan1_k(const int* __restrict__ deg,
                                               int* __restrict__ row_start,
                                               int* __restrict__ bsums) {
    __shared__ int sm[256];
    int tid = threadIdx.x;
    int i = blockIdx.x * 256 + tid;
    int v = (i < N_NODES) ? deg[i] : 0;
    sm[tid] = v;
    __syncthreads();
    #pragma unroll
    for (int off = 1; off < 256; off <<= 1) {
        int t = (tid >= off) ? sm[tid - off] : 0;
        __syncthreads();
        sm[tid] += t;
        __syncthreads();
    }
    if (i < N_NODES) row_start[i] = sm[tid] - v;  // exclusive within block
    if (tid == 255) bsums[blockIdx.x] = sm[255];
}

__global__ __launch_bounds__(256) void scan2_k(int* __restrict__ bsums, int nb) {
    __shared__ int sm[256];
    int tid = threadIdx.x;
    int v = (tid < nb) ? bsums[tid] : 0;
    sm[tid] = v;
    __syncthreads();
    #pragma unroll
    for (int off = 1; off < 256; off <<= 1) {
        int t = (tid >= off) ? sm[tid - off] : 0;
        __syncthreads();
        sm[tid] += t;
        __syncthreads();
    }
    if (tid < nb) bsums[tid] = sm[tid] - v;  // exclusive block offsets
}

__global__ __launch_bounds__(256) void scan3_k(int* __restrict__ row_start,
                                               const int* __restrict__ bsums) {
    int i = blockIdx.x * 256 + threadIdx.x;
    if (i < N_NODES) row_start[i] += bsums[blockIdx.x];
    if (i == 0) row_start[N_NODES] = N_EDGES;
}

__global__ __launch_bounds__(256) void fill_k(const int* __restrict__ ei,
                                              const int* __restrict__ row_start,
                                              int* __restrict__ cursor,
                                              int* __restrict__ csr_src) {
    int e = blockIdx.x * 256 + threadIdx.x;
    if (e < N_EDGES) {
        int s = ei[e];
        int d = ei[N_EDGES + e];
        if ((unsigned)d < N_NODES && (unsigned)s < N_NODES) {
            int pos = row_start[d] + atomicAdd(&cursor[d], 1);
            if ((unsigned)pos < N_EDGES) csr_src[pos] = s;
        }
    }
}

// ---------------------------------------------------------------------------
// fp32 GEMM: C[M][N] tile BM x 64 per block, 256 threads, micro-tile TM x 4.
// BK=16, double-buffered LDS, one barrier per K-step. K=128 fixed.
// gemm1: <128,128,8> grid(391,2); gemm2: <64,64,4> grid(782,1).
// __launch_bounds__(256,4) caps VGPR at 128 (est ~75) -> 4+ waves/SIMD.
// ---------------------------------------------------------------------------
template <int N, int BM, int TM>
__global__ __launch_bounds__(256, 4) void gemm_k(const float* __restrict__ A,
                                                 const float* __restrict__ B,
                                                 float* __restrict__ C, int M) {
    constexpr int K = 128, BK = 16, BN = 64, TN = 4;
    constexpr int NT = K / BK;   // 8 K-tiles
    constexpr int AR = BM / 64;  // A staging float4s per thread (2 or 1)

    __shared__ float AsT[2][BK][BM + 4];
    __shared__ float Bs[2][BK][BN];

    const int tid = threadIdx.x;
    const int tx = tid & 15, ty = tid >> 4;
    const int m0 = ty * TM, n0 = tx * TN;
    const int blockM = blockIdx.x * BM;
    const int nBase = blockIdx.y * BN;

    const int arow = tid >> 2;          // 0..63
    const int akq  = (tid & 3) * 4;     // k-quad
    const int brow = tid >> 4;          // 0..15
    const int bq   = (tid & 15) * 4;    // col-quad

    float4 aS[AR], bS;
    const float* Aptr[AR];
    #pragma unroll
    for (int p = 0; p < AR; ++p) {
        int r = blockM + arow + p * 64;
        r = r < M ? r : M - 1;
        Aptr[p] = A + (size_t)r * K + akq;
    }
    const float* Bptr = B + (size_t)brow * N + nBase + bq;

    float acc[TM][TN] = {};

    auto gload = [&](int kt) {
        #pragma unroll
        for (int p = 0; p < AR; ++p) aS[p] = *(const float4*)&Aptr[p][kt * BK];
        bS = *(const float4*)&Bptr[(size_t)kt * BK * N];
    };
    auto lstore = [&](int buf) {
        #pragma unroll
        for (int p = 0; p < AR; ++p) {
            AsT[buf][akq + 0][arow + p * 64] = aS[p].x;
            AsT[buf][akq + 1][arow + p * 64] = aS[p].y;
            AsT[buf][akq + 2][arow + p * 64] = aS[p].z;
            AsT[buf][akq + 3][arow + p * 64] = aS[p].w;
        }
        *(float4*)&Bs[buf][brow][bq] = bS;
    };
    auto compute = [&](int buf) {
        #pragma unroll
        for (int k = 0; k < BK; ++k) {
            float a[TM], b[TN];
            #pragma unroll
            for (int i = 0; i < TM; i += 4) {
                float4 t = *(const float4*)&AsT[buf][k][m0 + i];
                a[i] = t.x; a[i + 1] = t.y; a[i + 2] = t.z; a[i + 3] = t.w;
            }
            float4 tb = *(const float4*)&Bs[buf][k][n0];
            b[0] = tb.x; b[1] = tb.y; b[2] = tb.z; b[3] = tb.w;
            #pragma unroll
            for (int i = 0; i < TM; ++i)
                #pragma unroll
                for (int j = 0; j < TN; ++j)
                    acc[i][j] = fmaf(a[i], b[j], acc[i][j]);
        }
    };

    gload(0); lstore(0);
    __syncthreads();
    #pragma unroll 2
    for (int kt = 0; kt < NT; ++kt) {
        if (kt + 1 < NT) gload(kt + 1);
        compute(kt & 1);
        if (kt + 1 < NT) {
            // safe: buf^1's readers all passed the previous barrier already
            lstore((kt + 1) & 1);
            __syncthreads();
        }
    }

    #pragma unroll
    for (int i = 0; i < TM; ++i) {
        int row = blockM + m0 + i;
        if (row < M) {
            *(float4*)&C[(size_t)row * N + nBase + n0] =
                make_float4(acc[i][0], acc[i][1], acc[i][2], acc[i][3]);
        }
    }
}

// ---------------------------------------------------------------------------
// Aggregation: one wave (64 lanes) per node.
// F=128: lane holds float2; F=64: lane holds float.
// out_v = d_v * (sum_edges d_s * h_s + d_v * h_v) + bias  [, relu]
// ---------------------------------------------------------------------------
template <int F, bool RELU>
__global__ __launch_bounds__(256) void agg_k(const float* __restrict__ h,
                                             const float* __restrict__ dinv,
                                             const int* __restrict__ row_start,
                                             const int* __restrict__ csr_src,
                                             const float* __restrict__ bias,
                                             float* __restrict__ out) {
    constexpr int VEC = F / 64;  // 2 or 1
    int wid = (blockIdx.x * 256 + threadIdx.x) >> 6;
    int lane = threadIdx.x & 63;
    if (wid >= N_NODES) return;
    int v = wid;
    float dv = dinv[v];

    float acc0, acc1 = 0.f;
    const float* hv = h + (size_t)v * F;
    if constexpr (VEC == 2) {
        float2 t = *(const float2*)&hv[lane * 2];
        acc0 = dv * t.x; acc1 = dv * t.y;
    } else {
        acc0 = dv * hv[lane];
    }

    int e0 = row_start[v], e1 = row_start[v + 1];
    for (int e = e0; e < e1; e += 64) {
        int cnt = min(64, e1 - e);
        int s = 0; float w = 0.f;
        if (lane < cnt) { s = csr_src[e + lane]; w = dinv[s]; }
        for (int j = 0; j < cnt; ++j) {
            int ss = __shfl(s, j);
            float ww = __shfl(w, j);
            const float* hs = h + (size_t)ss * F;
            if constexpr (VEC == 2) {
                float2 t = *(const float2*)&hs[lane * 2];
                acc0 = fmaf(ww, t.x, acc0); acc1 = fmaf(ww, t.y, acc1);
            } else {
                acc0 = fmaf(ww, hs[lane], acc0);
            }
        }
    }

    if constexpr (VEC == 2) {
        float o0 = dv * acc0 + bias[lane * 2];
        float o1 = dv * acc1 + bias[lane * 2 + 1];
        if (RELU) { o0 = fmaxf(o0, 0.f); o1 = fmaxf(o1, 0.f); }
        *(float2*)&out[(size_t)v * F + lane * 2] = make_float2(o0, o1);
    } else {
        float o0 = dv * acc0 + bias[lane];
        if (RELU) o0 = fmaxf(o0, 0.f);
        out[(size_t)v * F + lane] = o0;
    }
}

extern "C" void kernel_launch(void* const* d_in, const int* in_sizes, int n_in,
                              void* d_out, int out_size, void* d_ws, size_t ws_size,
                              hipStream_t stream) {
    const float* x        = (const float*)d_in[0];   // [50000,128]
    const float* W1       = (const float*)d_in[1];   // [128,128]
    const float* b1       = (const float*)d_in[2];   // [128]
    const float* W2       = (const float*)d_in[3];   // [128,64]
    const float* b2       = (const float*)d_in[4];   // [64]
    const int*   ei       = (const int*)d_in[5];     // [2,800000] delivered as int32
    float* out = (float*)d_out;                      // [50000,64]

    char* ws = (char*)d_ws;
    int*   deg       = (int*)(ws + OFF_DEG);
    int*   cursor    = (int*)(ws + OFF_CUR);
    int*   row_start = (int*)(ws + OFF_ROW);
    int*   bsums     = (int*)(ws + OFF_BS);
    float* dinv      = (float*)(ws + OFF_DINV);
    int*   csr_src   = (int*)(ws + OFF_CSR);
    float* h1        = (float*)(ws + OFF_H1);
    float* out1      = (float*)(ws + OFF_OUT1);
    float* h2        = (float*)(ws + OFF_H1);  // reuse: h1 dead after agg1

    // zero deg + cursor
    hipMemsetAsync(ws + OFF_DEG, 0, OFF_ROW - OFF_DEG, stream);

    const int nbE = (N_EDGES + 255) / 256;   // 3125
    const int nbN = (N_NODES + 255) / 256;   // 196

    count_deg_k<<<nbE, 256, 0, stream>>>(ei, deg);
    dinv_k<<<nbN, 256, 0, stream>>>(deg, dinv);
    scan1_k<<<nbN, 256, 0, stream>>>(deg, row_start, bsums);
    scan2_k<<<1, 256, 0, stream>>>(bsums, nbN);
    scan3_k<<<nbN, 256, 0, stream>>>(row_start, bsums);
    fill_k<<<nbE, 256, 0, stream>>>(ei, row_start, cursor, csr_src);

    // gemm1: C[50000,128] = x @ W1 ; BM=128, grid (391, 2)
    gemm_k<128, 128, 8><<<dim3((N_NODES + 127) / 128, 2), 256, 0, stream>>>(x, W1, h1, N_NODES);
    agg_k<128, true><<<(N_NODES + 3) / 4, 256, 0, stream>>>(h1, dinv, row_start, csr_src, b1, out1);
    // gemm2: C[50000,64] = out1 @ W2 ; BM=64, grid (782, 1)
    gemm_k<64, 64, 4><<<dim3((N_NODES + 63) / 64, 1), 256, 0, stream>>>(out1, W2, h2, N_NODES);
    agg_k<64, false><<<(N_NODES + 3) / 4, 256, 0, stream>>>(h2, dinv, row_start, csr_src, b2, out);
}